// Round 7
// baseline (353341.431 us; speedup 1.0000x reference)
//
#include <hip/hip_runtime.h>

#define BB 128      // batch
#define TT 1024     // seq len
#define II 64       // input size
#define HH 512      // hidden
#define KK 576      // II + HH
#define NBLK 256    // one block per pair of h-columns
#define NTHR 256

// One kernel per timestep. Kernel boundary = grid barrier + coherence (CP-
// managed L2 maintenance; rounds 1-5 proved every software alternative costs
// 70-300us/step). All memory ops are plain cached loads/stores.
// Block g owns h-cols {2g,2g+1}: stages its 8 W rows (L2-hot) + full [x_t|h]
// in 9 LDS chunks (reg-prefetch pipeline), f32 (2 gate-rows x 2 batch) dots,
// c slice persistent in cbuf, h double-buffered in hbuf.
// Block 0 additionally computes y[:,t-1] from the h it stages (1-step delay).
__global__ __launch_bounds__(NTHR, 1)
void lstm_step(const float* __restrict__ x,
               const float* __restrict__ W_ih,
               const float* __restrict__ W_hh,
               const float* __restrict__ b_ih,
               const float* __restrict__ b_hh,
               const float* __restrict__ W_fc,
               const float* __restrict__ b_fc,
               float* __restrict__ out,
               float* __restrict__ hbuf,   // 2 x [BB][HH] f32
               float* __restrict__ cbuf,   // [NBLK][256] f32
               int t)
{
    __shared__ float Wl[8][KK];      // 18432B  rows: gate*2 + jj (i,i,f,f,g,g,o,o)
    __shared__ float vx[BB][68];     // 34816B  one 64-wide K chunk, pad 68
    __shared__ float gl[8][BB];      //  4096B
    __shared__ float yl[2][BB];      //  1024B
    __shared__ float wfc[HH];        //  2048B
    __shared__ float bias[8];        //    32B

    const int u  = threadIdx.x;
    const int g  = blockIdx.x;
    const int j0 = g << 1;
    const bool doy = (g == 0);

    const int bA  = u & 63, bB2 = bA + 64;   // compute-tile batch rows
    const int rp  = u >> 6;
    const int rA  = rp << 1, rB = rA + 1;    // compute-tile gate rows
    const int ub  = u & 127, ujj = u >> 7;   // update / y mapping
    const int xb  = u >> 4, xq = u & 15;     // 16B-per-lane staging mapping

    const float bfc = b_fc[0];

    const float* __restrict__ hsrc = hbuf + (size_t)(t & 1) * BB * HH;
    float*       __restrict__ hdst = hbuf + (size_t)((t + 1) & 1) * BB * HH;

    // ---- per-step W staging (L2-hot after step 0): 1152 float4 / block ----
    {
        const float4* __restrict__ Wih4 = (const float4*)W_ih;   // [4H][16]
        const float4* __restrict__ Whh4 = (const float4*)W_hh;   // [4H][128]
        float4* __restrict__ Wl4 = (float4*)&Wl[0][0];           // [8][144]
        #pragma unroll
        for (int i = 0; i < 5; ++i) {
            const int idx = u + (i << 8);
            if (idx < 1152) {
                const int r  = idx / 144, c4 = idx - r * 144;
                const int R  = (r >> 1) * HH + j0 + (r & 1);
                const float4 v = (c4 < 16) ? Wih4[R * 16 + c4]
                                           : Whh4[R * 128 + (c4 - 16)];
                Wl4[r * 144 + c4] = v;
            }
        }
    }
    if (u < 8) {
        const int R = (u >> 1) * HH + j0 + (u & 1);
        bias[u] = b_ih[R] + b_hh[R];
    }
    if (doy) for (int k = u; k < HH; k += NTHR) wfc[k] = W_fc[k];

    float creg = cbuf[(g << 8) + u];          // zeroed by memset at t==0
    float4 rx4[8], ha[8], hb[8];

#define LOAD_X { _Pragma("unroll")                                               \
    for (int r8 = 0; r8 < 8; ++r8)                                               \
        rx4[r8] = *(const float4*)(x + ((size_t)(xb + 16*r8) * TT + t) * II      \
                                     + (xq << 2)); }

#define STAGE_X { _Pragma("unroll")                                              \
    for (int r8 = 0; r8 < 8; ++r8)                                               \
        *(float4*)&vx[xb + 16*r8][xq << 2] = rx4[r8]; }

    // h chunk N (1..8) = h cols [(N-1)*64, N*64); 16 lanes x 16B per row
#define ISSUE_H(R, N) { const float4* __restrict__ h4_ = (const float4*)hsrc;    \
    _Pragma("unroll")                                                            \
    for (int i = 0; i < 8; ++i) {                                                \
        const int flat_ = u + (i << 8);                                          \
        (R)[i] = h4_[(size_t)(flat_ >> 4) * 128 + (((N)-1) << 4) + (flat_ & 15)]; \
    } }

#define STAGE_H(R) { _Pragma("unroll")                                           \
    for (int i = 0; i < 8; ++i) {                                                \
        const int flat_ = u + (i << 8);                                          \
        *(float4*)&vx[flat_ >> 4][(flat_ & 15) << 2] = (R)[i];                   \
    } }

#define COMPUTE(CH) {                                                            \
    const float* wra_ = &Wl[rA][(CH) << 6];                                      \
    const float* wrb_ = &Wl[rB][(CH) << 6];                                      \
    const float* va_  = &vx[bA][0];                                              \
    const float* vb_  = &vx[bB2][0];                                             \
    _Pragma("unroll")                                                            \
    for (int k4 = 0; k4 < 16; ++k4) {                                            \
        const float4 wa = *(const float4*)(wra_ + (k4 << 2));                    \
        const float4 wb = *(const float4*)(wrb_ + (k4 << 2));                    \
        const float4 pa = *(const float4*)(va_ + (k4 << 2));                     \
        const float4 pb = *(const float4*)(vb_ + (k4 << 2));                     \
        a00 += wa.x*pa.x + wa.y*pa.y + wa.z*pa.z + wa.w*pa.w;                    \
        a01 += wa.x*pb.x + wa.y*pb.y + wa.z*pb.z + wa.w*pb.w;                    \
        a10 += wb.x*pa.x + wb.y*pa.y + wb.z*pa.z + wb.w*pa.w;                    \
        a11 += wb.x*pb.x + wb.y*pb.y + wb.z*pb.z + wb.w*pb.w; } }

#define YPART(CH) if (doy && t > 0) {                                            \
    const float* wf_ = &wfc[(((CH)-1) << 6) + (ujj << 5)];                       \
    const float* vv_ = &vx[ub][ujj << 5];                                        \
    _Pragma("unroll")                                                            \
    for (int k4 = 0; k4 < 8; ++k4) {                                             \
        const float4 f4 = *(const float4*)(wf_ + (k4 << 2));                     \
        const float4 v4 = *(const float4*)(vv_ + (k4 << 2));                     \
        yacc += f4.x*v4.x + f4.y*v4.y + f4.z*v4.z + f4.w*v4.w; } }

    float a00 = 0.f, a01 = 0.f, a10 = 0.f, a11 = 0.f, yacc = 0.f;

    LOAD_X;
    __syncthreads();                 // Wl/bias/wfc ready
    STAGE_X; ISSUE_H(ha, 1);
    __syncthreads();  COMPUTE(0);
    __syncthreads();  STAGE_H(ha); ISSUE_H(hb, 2);
    __syncthreads();  COMPUTE(1); YPART(1);
    __syncthreads();  STAGE_H(hb); ISSUE_H(ha, 3);
    __syncthreads();  COMPUTE(2); YPART(2);
    __syncthreads();  STAGE_H(ha); ISSUE_H(hb, 4);
    __syncthreads();  COMPUTE(3); YPART(3);
    __syncthreads();  STAGE_H(hb); ISSUE_H(ha, 5);
    __syncthreads();  COMPUTE(4); YPART(4);
    __syncthreads();  STAGE_H(ha); ISSUE_H(hb, 6);
    __syncthreads();  COMPUTE(5); YPART(5);
    __syncthreads();  STAGE_H(hb); ISSUE_H(ha, 7);
    __syncthreads();  COMPUTE(6); YPART(6);
    __syncthreads();  STAGE_H(ha); ISSUE_H(hb, 8);
    __syncthreads();  COMPUTE(7); YPART(7);
    __syncthreads();  STAGE_H(hb);
    __syncthreads();  COMPUTE(8); YPART(8);

    if (doy && t > 0) yl[ujj][ub] = yacc;
    gl[rA][bA]  = a00 + bias[rA];
    gl[rA][bB2] = a01 + bias[rA];
    gl[rB][bA]  = a10 + bias[rB];
    gl[rB][bB2] = a11 + bias[rB];
    __syncthreads();

    {   // c/h update: (128 b) x (2 jj); plain cached stores
        const float gi = gl[0 + ujj][ub];
        const float gf = gl[2 + ujj][ub];
        const float gg = gl[4 + ujj][ub];
        const float go = gl[6 + ujj][ub];
        const float si = 1.f / (1.f + expf(-gi));
        const float sf = 1.f / (1.f + expf(-gf));
        const float tg = tanhf(gg);
        const float so = 1.f / (1.f + expf(-go));
        const float c  = sf * creg + si * tg;
        cbuf[(g << 8) + u] = c;
        hdst[(size_t)ub * HH + j0 + ujj] = so * tanhf(c);
        if (doy && t > 0 && u < BB)
            out[(size_t)u * TT + (t - 1)] = yl[0][u] + yl[1][u] + bfc;
    }
#undef LOAD_X
#undef STAGE_X
#undef ISSUE_H
#undef STAGE_H
#undef COMPUTE
#undef YPART
}

// y[:, T-1] from h_{T-1} (hbuf buffer 0, since TT is even)
__global__ void lstm_tail(const float* __restrict__ W_fc,
                          const float* __restrict__ b_fc,
                          const float* __restrict__ hbuf,
                          float* __restrict__ out)
{
    const int u = threadIdx.x;
    if (u < BB) {
        const float4* __restrict__ h4 = (const float4*)hbuf;
        const float4* __restrict__ w4 = (const float4*)W_fc;
        float acc = 0.f;
        #pragma unroll 8
        for (int k = 0; k < 128; ++k) {
            const float4 hv = h4[(size_t)u * 128 + k];
            const float4 wv = w4[k];
            acc += hv.x*wv.x + hv.y*wv.y + hv.z*wv.z + hv.w*wv.w;
        }
        out[(size_t)u * TT + (TT - 1)] = acc + b_fc[0];
    }
}

extern "C" void kernel_launch(void* const* d_in, const int* in_sizes, int n_in,
                              void* d_out, int out_size, void* d_ws, size_t ws_size,
                              hipStream_t stream) {
    (void)in_sizes; (void)n_in; (void)out_size; (void)ws_size;
    const float* x    = (const float*)d_in[0];
    const float* W_ih = (const float*)d_in[1];
    const float* W_hh = (const float*)d_in[2];
    const float* b_ih = (const float*)d_in[3];
    const float* b_hh = (const float*)d_in[4];
    const float* W_fc = (const float*)d_in[5];
    const float* b_fc = (const float*)d_in[6];
    float* out = (float*)d_out;

    float* hbuf = (float*)d_ws;                                  // 512 KB
    float* cbuf = (float*)((char*)d_ws + 2u * BB * HH * 4u);     // 256 KB

    // zero h buffer 0 (read at t=0) and all of cbuf -> replay-deterministic
    (void)hipMemsetAsync(d_ws, 0, (2u * BB * HH + NBLK * 2 * BB) * 4u, stream);

    for (int t = 0; t < TT; ++t)
        hipLaunchKernelGGL(lstm_step, dim3(NBLK), dim3(NTHR), 0, stream,
                           x, W_ih, W_hh, b_ih, b_hh, W_fc, b_fc, out,
                           hbuf, cbuf, t);
    hipLaunchKernelGGL(lstm_tail, dim3(1), dim3(128), 0, stream,
                       W_fc, b_fc, hbuf, out);
}

// Round 8
// 334108.032 us; speedup vs baseline: 1.0576x; 1.0576x over previous
//
#include <hip/hip_runtime.h>

#define BB 128      // batch
#define TT 1024     // seq len
#define II 64       // input size
#define HH 512      // hidden
#define KK 576      // II + HH
#define NBLK 256    // one block per pair of h-columns
#define NTHR 256

typedef unsigned int u32;

// Persistent LSTM. Cost model from rounds 1-7:
//   r1/r3 (~70us/step): 256 serialized same-line far-atomic RMWs per step.
//   r4/r5 (~330us/step): uncached bulk reads -> 4x HBM amplification.
//   r7 (~345us/step): per-step kernel dispatch overhead.
// This version: r4's RMW-free flag barrier (parallel relaxed stores +
// per-thread polls) + CACHED bulk h exchange + ONE release fence
// (buffer_wbl2) and ONE acquire fence (buffer_inv) per block per step.
// hbuf transposed [j][b]: each block owns whole 64B lines of h (its 2 rows)
// -> no cross-XCD partial-line writeback clobber.
__global__ __launch_bounds__(NTHR, 1)
void lstm_persist(const float* __restrict__ x,
                  const float* __restrict__ W_ih,
                  const float* __restrict__ W_hh,
                  const float* __restrict__ b_ih,
                  const float* __restrict__ b_hh,
                  const float* __restrict__ W_fc,
                  const float* __restrict__ b_fc,
                  float* __restrict__ out,
                  float* __restrict__ hbuf,   // 2 x [HH][BB] f32 (transposed)
                  u32*   __restrict__ flags)  // [NBLK] monotonic step counters
{
    __shared__ float Wl[8][KK];      // 18432B  rows: gate*2 + jj (i,i,f,f,g,g,o,o)
    __shared__ float vx[BB][68];     // 34816B  one 64-wide K chunk of [x|h], [b][k]
    __shared__ float gl[8][BB];      //  4096B
    __shared__ float yl[2][BB];      //  1024B
    __shared__ float wfc[HH];        //  2048B
    __shared__ float bias[8];        //    32B  => 60448B (<64KB coop limit)

    const int u  = threadIdx.x;
    const int g  = blockIdx.x;
    const int j0 = g << 1;
    const bool doy = (g == 0);

    // ---- one-time weight staging ----
    for (int r = 0; r < 8; ++r) {
        const int R = (r >> 1) * HH + j0 + (r & 1);
        for (int k = u; k < KK; k += NTHR)
            Wl[r][k] = (k < II) ? W_ih[(size_t)R * II + k]
                                : W_hh[(size_t)R * HH + (k - II)];
    }
    if (u < 8) {
        const int R = (u >> 1) * HH + j0 + (u & 1);
        bias[u] = b_ih[R] + b_hh[R];
    }
    if (doy) for (int k = u; k < HH; k += NTHR) wfc[k] = W_fc[k];

    const float bfc = b_fc[0];
    const int   bA  = u & 63, bB2 = bA + 64;   // compute-tile batch rows
    const int   rp  = u >> 6;
    const int   rA  = rp << 1, rB = rA + 1;    // compute-tile gate rows
    const int   ub  = u & 127, ujj = u >> 7;   // update / y mapping
    const int   xb  = u >> 4, xq = u & 15;     // x staging mapping
    float creg = 0.f;
    float4 rx4[8];                             // x_t prefetch
    float  rha[32], rhb[32];                   // h chunk ping-pong

#define LOAD_X(T) { _Pragma("unroll")                                            \
    for (int r8 = 0; r8 < 8; ++r8)                                               \
        rx4[r8] = *(const float4*)(x + ((size_t)(xb + 16*r8) * TT + (T)) * II    \
                                     + (xq << 2)); }

#define STAGE_X { _Pragma("unroll")                                              \
    for (int r8 = 0; r8 < 8; ++r8)                                               \
        *(float4*)&vx[xb + 16*r8][xq << 2] = rx4[r8]; }

    // h chunk N (1..8) = hT rows [(N-1)*64, N*64). unit = (b, 4-k group):
    // 4 coalesced b32 reads (lanes walk b) per unit.
#define ISSUE_HT(R, N) {                                                         \
    const float* hp_ = hsrcT + (size_t)(((N)-1) << 6) * BB;                      \
    _Pragma("unroll")                                                            \
    for (int i = 0; i < 8; ++i) {                                                \
        const int unit_ = u + (i << 8);                                          \
        const int b_ = unit_ & 127, kq_ = unit_ >> 7;                            \
        const float* p_ = hp_ + (size_t)(kq_ << 2) * BB + b_;                    \
        (R)[4*i+0] = p_[0*BB]; (R)[4*i+1] = p_[1*BB];                            \
        (R)[4*i+2] = p_[2*BB]; (R)[4*i+3] = p_[3*BB]; } }

#define STAGE_HT(R) { _Pragma("unroll")                                          \
    for (int i = 0; i < 8; ++i) {                                                \
        const int unit_ = u + (i << 8);                                          \
        const int b_ = unit_ & 127, kq_ = unit_ >> 7;                            \
        float4 f_;                                                               \
        f_.x = (R)[4*i+0]; f_.y = (R)[4*i+1];                                    \
        f_.z = (R)[4*i+2]; f_.w = (R)[4*i+3];                                    \
        *(float4*)&vx[b_][kq_ << 2] = f_; } }

#define COMPUTE(CH) {                                                            \
    const float* wra_ = &Wl[rA][(CH) << 6];                                      \
    const float* wrb_ = &Wl[rB][(CH) << 6];                                      \
    const float* va_  = &vx[bA][0];                                              \
    const float* vb_  = &vx[bB2][0];                                             \
    _Pragma("unroll")                                                            \
    for (int k4 = 0; k4 < 16; ++k4) {                                            \
        const float4 wa = *(const float4*)(wra_ + (k4 << 2));                    \
        const float4 wb = *(const float4*)(wrb_ + (k4 << 2));                    \
        const float4 pa = *(const float4*)(va_ + (k4 << 2));                     \
        const float4 pb = *(const float4*)(vb_ + (k4 << 2));                     \
        a00 += wa.x*pa.x + wa.y*pa.y + wa.z*pa.z + wa.w*pa.w;                    \
        a01 += wa.x*pb.x + wa.y*pb.y + wa.z*pb.z + wa.w*pb.w;                    \
        a10 += wb.x*pa.x + wb.y*pa.y + wb.z*pa.z + wb.w*pa.w;                    \
        a11 += wb.x*pb.x + wb.y*pb.y + wb.z*pb.z + wb.w*pb.w; } }

#define YPART(CH) if (doy && t > 0) {                                            \
    const float* wf_ = &wfc[(((CH)-1) << 6) + (ujj << 5)];                       \
    const float* vv_ = &vx[ub][ujj << 5];                                        \
    _Pragma("unroll")                                                            \
    for (int k4 = 0; k4 < 8; ++k4) {                                             \
        const float4 f4 = *(const float4*)(wf_ + (k4 << 2));                     \
        const float4 v4 = *(const float4*)(vv_ + (k4 << 2));                     \
        yacc += f4.x*v4.x + f4.y*v4.y + f4.z*v4.z + f4.w*v4.w; } }

    LOAD_X(0);   // hbuf buffer0 + flags zeroed by stream-ordered memset

    for (int t = 0; t < TT; ++t) {
        const float* __restrict__ hsrcT = hbuf + (size_t)(t & 1) * HH * BB;
        float*       __restrict__ hdstT = hbuf + (size_t)((t + 1) & 1) * HH * BB;

        float a00 = 0.f, a01 = 0.f, a10 = 0.f, a11 = 0.f, yacc = 0.f;

        // pipeline: ISSUE after the vx-ready barrier -> loads ride under COMPUTE
        __syncthreads(); STAGE_X;
        __syncthreads(); ISSUE_HT(rha, 1); COMPUTE(0);
        __syncthreads(); STAGE_HT(rha);
        __syncthreads(); ISSUE_HT(rhb, 2); COMPUTE(1); YPART(1);
        __syncthreads(); STAGE_HT(rhb);
        __syncthreads(); ISSUE_HT(rha, 3); COMPUTE(2); YPART(2);
        __syncthreads(); STAGE_HT(rha);
        __syncthreads(); ISSUE_HT(rhb, 4); COMPUTE(3); YPART(3);
        __syncthreads(); STAGE_HT(rhb);
        __syncthreads(); ISSUE_HT(rha, 5); COMPUTE(4); YPART(4);
        __syncthreads(); STAGE_HT(rha);
        __syncthreads(); ISSUE_HT(rhb, 6); COMPUTE(5); YPART(5);
        __syncthreads(); STAGE_HT(rhb);
        __syncthreads(); ISSUE_HT(rha, 7); COMPUTE(6); YPART(6);
        __syncthreads(); STAGE_HT(rha);
        __syncthreads(); ISSUE_HT(rhb, 8); COMPUTE(7); YPART(7);
        __syncthreads(); STAGE_HT(rhb);
        __syncthreads(); COMPUTE(8); YPART(8);

        if (doy && t > 0) yl[ujj][ub] = yacc;
        gl[rA][bA]  = a00 + bias[rA];
        gl[rA][bB2] = a01 + bias[rA];
        gl[rB][bA]  = a10 + bias[rB];
        gl[rB][bB2] = a11 + bias[rB];
        __syncthreads();

        {   // c/h update: (128 b) x (2 jj); PLAIN CACHED h store (own lines)
            const float gi = gl[0 + ujj][ub];
            const float gf = gl[2 + ujj][ub];
            const float gg = gl[4 + ujj][ub];
            const float go = gl[6 + ujj][ub];
            const float si = 1.f / (1.f + expf(-gi));
            const float sf = 1.f / (1.f + expf(-gf));
            const float tg = tanhf(gg);
            const float so = 1.f / (1.f + expf(-go));
            const float c  = sf * creg + si * tg;
            creg = c;
            hdstT[(size_t)(j0 + ujj) * BB + ub] = so * tanhf(c);
            if (doy && t > 0 && u < BB)
                out[(size_t)u * TT + (t - 1)] = yl[0][u] + yl[1][u] + bfc;
        }

        // ---- barrier: release-fence + flag store; poll; acquire-fence ----
        __syncthreads();   // all waves' h stores complete (at local L2)
        if (u == 0) {
            __builtin_amdgcn_fence(__ATOMIC_RELEASE, "agent");  // buffer_wbl2
            __hip_atomic_store(&flags[g], (u32)(t + 1),
                               __ATOMIC_RELAXED, __HIP_MEMORY_SCOPE_AGENT);
        }
        if (t + 1 < TT) LOAD_X(t + 1);   // x is read-only: safe before acquire
        {
            const u32 want = (u32)(t + 1);
            while (__hip_atomic_load(&flags[u], __ATOMIC_RELAXED,
                                     __HIP_MEMORY_SCOPE_AGENT) < want)
                __builtin_amdgcn_s_sleep(1);
        }
        __syncthreads();   // all 256 flags confirmed
        if (u == 0)
            __builtin_amdgcn_fence(__ATOMIC_ACQUIRE, "agent"); // buffer_inv
        __syncthreads();
    }

    // ---- epilogue: y for the final h (block 0 only) ----
    if (doy) {
        const float* __restrict__ hsrcT = hbuf + (size_t)(TT & 1) * HH * BB;
        const int t = 1;   // enable YPART guard
        float yacc = 0.f;
        #pragma unroll 1
        for (int n = 1; n <= 8; ++n) {
            __syncthreads();
            ISSUE_HT(rha, n);
            STAGE_HT(rha);
            __syncthreads();
            YPART(n);
        }
        (void)t;
        yl[ujj][ub] = yacc;
        __syncthreads();
        if (u < BB) out[(size_t)u * TT + (TT - 1)] = yl[0][u] + yl[1][u] + bfc;
    }
#undef LOAD_X
#undef STAGE_X
#undef ISSUE_HT
#undef STAGE_HT
#undef COMPUTE
#undef YPART
}

extern "C" void kernel_launch(void* const* d_in, const int* in_sizes, int n_in,
                              void* d_out, int out_size, void* d_ws, size_t ws_size,
                              hipStream_t stream) {
    (void)in_sizes; (void)n_in; (void)out_size; (void)ws_size;
    const float* x    = (const float*)d_in[0];
    const float* W_ih = (const float*)d_in[1];
    const float* W_hh = (const float*)d_in[2];
    const float* b_ih = (const float*)d_in[3];
    const float* b_hh = (const float*)d_in[4];
    const float* W_fc = (const float*)d_in[5];
    const float* b_fc = (const float*)d_in[6];
    float* out = (float*)d_out;

    u32*   flags = (u32*)d_ws;                       // 256 words (4KB reserved)
    float* hbuf  = (float*)((char*)d_ws + 4096);     // 2*[HH][BB] = 512KB

    // zero flags + h buffer 0 (read at t=0) each call -> replay-deterministic
    (void)hipMemsetAsync(d_ws, 0, 4096 + (size_t)HH * BB * sizeof(float), stream);

    void* args[] = {(void*)&x, (void*)&W_ih, (void*)&W_hh, (void*)&b_ih,
                    (void*)&b_hh, (void*)&W_fc, (void*)&b_fc, (void*)&out,
                    (void*)&hbuf, (void*)&flags};
    hipError_t e = hipLaunchCooperativeKernel((const void*)lstm_persist,
                                              dim3(NBLK), dim3(NTHR), args, 0, stream);
    if (e != hipSuccess) {
        hipLaunchKernelGGL(lstm_persist, dim3(NBLK), dim3(NTHR), 0, stream,
                           x, W_ih, W_hh, b_ih, b_hh, W_fc, b_fc, out, hbuf, flags);
    }
}